// Round 9
// baseline (396.212 us; speedup 1.0000x reference)
//
#include <hip/hip_runtime.h>

// 2-layer GRU (T=1000 serial, B=512) + FC + log_softmax.
// Pass 1: ax[b,t] = (x_t @ W1x + b1) * LOG2E-scales -> d_ws, per-lane (z,g).
// Pass 2: one wave per batch element, skewed layers (lanes 0..31 = GRU1 unit j
//         @ step t, lanes 32..51 = GRU2 unit j @ step t-1). Broadcast of h
//         via LDS: 1 ds_write_b32 + 13 uniform ds_read_b128 per step (DS pipe,
//         ~28 issue cyc) instead of 52 v_readlane (~416 VALU cyc @ ~8cyc each,
//         the measured r8 bottleneck). DS ops of one wave complete in order,
//         so write->read same address needs no fence. Dot = 104 scalar v_fmac
//         (quad elements consumed directly, no splat movs), 8 indep chains.

typedef float v4f __attribute__((ext_vector_type(4)));

constexpr int FBINS  = 40;
constexpr int L1     = 32;
constexpr int L2     = 20;
constexpr int L3     = 16;
constexpr int NCLASS = 10;
constexpr int T      = 1000;
constexpr int KTOT   = L1 + L2;   // 52
constexpr int NQUAD  = KTOT / 4;  // 13
constexpr float LOG2E = 1.4426950408889634f;
constexpr float LN2   = 0.6931471805599453f;

__device__ __forceinline__ float rl(float v, int l) {
    return __uint_as_float(__builtin_amdgcn_readlane(__float_as_uint(v), l));
}

// ---------------- pass 1: x-projection (pre-scaled by LOG2E / 2*LOG2E) ------
constexpr int TCH = 100;
__global__ __launch_bounds__(256) void xproj_kernel(
    const float* __restrict__ xg,
    const float* __restrict__ wz1, const float* __restrict__ bz1,
    const float* __restrict__ wh1, const float* __restrict__ bh1,
    float* __restrict__ ax, int t0, int tcnt, int segcap)
{
    __shared__ float xs[TCH * FBINS];
    const int tid = threadIdx.x, lane = tid & 63;
    const int b   = blockIdx.x;
    const int lt0 = blockIdx.y * TCH;
    const int cnt = min(TCH, tcnt - lt0);
    const float* src = xg + ((size_t)b * T + t0 + lt0) * FBINS;
    const int ndw = cnt * FBINS;
    for (int i = tid; i < ndw; i += 256) xs[i] = src[i];
    __syncthreads();

    const int j = lane & 31;
    const float* wp = (lane < 32) ? wz1 : wh1;   // lane<32: z-gate, else g-gate
    const float scale = (lane < 32) ? LOG2E : (2.0f * LOG2E);
    float w[FBINS];
    #pragma unroll
    for (int k = 0; k < FBINS; ++k) w[k] = wp[k * L1 + j] * scale;
    const float bias = ((lane < 32) ? bz1[j] : bh1[j]) * scale;
    const int slot = j * 2 + (lane >> 5);        // (z,g) interleaved pairs

    const int wv = tid >> 6;
    for (int lt = wv; lt < cnt; lt += 4) {
        const float* xp = xs + lt * FBINS;
        float a0 = bias, a1 = 0.f, a2 = 0.f, a3 = 0.f;
        #pragma unroll
        for (int k = 0; k < FBINS; k += 4) {
            a0 = fmaf(xp[k+0], w[k+0], a0);
            a1 = fmaf(xp[k+1], w[k+1], a1);
            a2 = fmaf(xp[k+2], w[k+2], a2);
            a3 = fmaf(xp[k+3], w[k+3], a3);
        }
        ax[((size_t)b * segcap + lt0 + lt) * 64 + slot] = (a0 + a1) + (a2 + a3);
    }
}

// ---------------- pass 2: skewed recurrence, LDS h-broadcast ----------------
constexpr int GS = 8;      // steps per prefetch group (double-buffered)
__global__ __launch_bounds__(64, 1) void rec_kernel(
    const float* __restrict__ ax,
    const float* __restrict__ wz1, const float* __restrict__ wh1,
    const float* __restrict__ wz2, const float* __restrict__ bz2,
    const float* __restrict__ wh2, const float* __restrict__ bh2,
    const float* __restrict__ w3,  const float* __restrict__ b3,
    const float* __restrict__ w4,  const float* __restrict__ b4,
    float* __restrict__ hws, float* __restrict__ outg,
    int tcnt, int segcap, int first, int last)
{
    __shared__ alignas(16) float hls[64];

    const int lane = threadIdx.x;
    const int b    = blockIdx.x;
    const int j    = lane & 31;
    const bool lo  = lane < 32;
    const int j2   = (j < L2) ? j : 0;           // clamp junk lanes 52..63

    // per-lane weight columns (pre-scaled): lower = GRU1 h-part (zero-padded
    // past k=32), upper = GRU2 full 52 rows.
    float wz[KTOT], wg[KTOT];
    #pragma unroll
    for (int k = 0; k < L1; ++k) {
        wz[k] = (lo ? wz1[(FBINS + k) * L1 + j] : wz2[k * L2 + j2]) * LOG2E;
        wg[k] = (lo ? wh1[(FBINS + k) * L1 + j] : wh2[k * L2 + j2]) * (2.0f * LOG2E);
    }
    #pragma unroll
    for (int k = 0; k < L2; ++k) {
        wz[L1 + k] = lo ? 0.f : wz2[(L1 + k) * L2 + j2] * LOG2E;
        wg[L1 + k] = lo ? 0.f : wh2[(L1 + k) * L2 + j2] * (2.0f * LOG2E);
    }
    const float initZ = bz2[j2] * LOG2E;          // upper lanes only
    const float initG = bh2[j2] * (2.0f * LOG2E);

    const float up0 = first ? 0.f : hws[b * 64 + 32 + j2];   // h2 restore
    float h = lo ? (first ? 0.f : hws[b * 64 + j]) : up0;

    const float2* axp = (const float2*)ax + (size_t)b * segcap * 32 + j;

    // pipeline state: shq holds the broadcast h quads for the NEXT dot
    v4f shq[NQUAD];
    hls[lane] = h;
    #pragma unroll
    for (int q = 0; q < NQUAD; ++q) shq[q] = ((const v4f*)hls)[q];

    auto step = [&](float2 axv, bool fix) {
        // dot: 104 scalar fmacs, 8 independent chains, consuming shq quads
        // in return order (quad 0 first)
        float az0 = lo ? axv.x : initZ, az1 = 0.f, az2 = 0.f, az3 = 0.f;
        float ag0 = lo ? axv.y : initG, ag1 = 0.f, ag2 = 0.f, ag3 = 0.f;
        #pragma unroll
        for (int q = 0; q < NQUAD; ++q) {
            az0 = fmaf(shq[q].x, wz[4*q+0], az0);
            ag0 = fmaf(shq[q].x, wg[4*q+0], ag0);
            az1 = fmaf(shq[q].y, wz[4*q+1], az1);
            ag1 = fmaf(shq[q].y, wg[4*q+1], ag1);
            az2 = fmaf(shq[q].z, wz[4*q+2], az2);
            ag2 = fmaf(shq[q].z, wg[4*q+2], ag2);
            az3 = fmaf(shq[q].w, wz[4*q+3], az3);
            ag3 = fmaf(shq[q].w, wg[4*q+3], ag3);
        }
        float z = (az0 + az1) + (az2 + az3);
        float g = (ag0 + ag1) + (ag2 + ag3);
        // activations (args pre-scaled by LOG2E / 2*LOG2E)
        float ez  = __builtin_amdgcn_exp2f(-z);
        float s   = __builtin_amdgcn_rcpf(1.f + ez);
        float eg  = __builtin_amdgcn_exp2f(-g);
        float r   = __builtin_amdgcn_rcpf(1.f + eg);
        float hp1 = 1.f + h;
        float d   = fmaf(2.f, r, -hp1);           // tanh(g) - h
        h = fmaf(s, d, h);                        // (1-z)h + z*tanh(g)
        if (fix) h = lo ? h : up0;                // round-0 skew fixup
        // broadcast for next step: write then 13 uniform b128 reads (in-order
        // DS pipe -> reads see the new h; latency hidden by act+loop of next)
        hls[lane] = h;
        #pragma unroll
        for (int q = 0; q < NQUAD; ++q) shq[q] = ((const v4f*)hls)[q];
    };

    // ---- pipelined loop, GS-step groups, double-buffered register prefetch
    float2 bufA[GS], bufB[GS];
    const int ng = tcnt / GS;                    // tcnt multiple of 8
    #pragma unroll
    for (int i = 0; i < GS; ++i) bufA[i] = axp[(size_t)i * 32];
    if (1 < ng) {
        #pragma unroll
        for (int i = 0; i < GS; ++i) bufB[i] = axp[(size_t)(GS + i) * 32];
    }

    step(bufA[0], true);                         // round 0: fix junk GRU2 out
    #pragma unroll
    for (int i = 1; i < GS; ++i) step(bufA[i], false);
    if (2 < ng) {
        #pragma unroll
        for (int i = 0; i < GS; ++i) bufA[i] = axp[(size_t)(2 * GS + i) * 32];
    }
    #pragma unroll 1
    for (int gp = 1; gp < ng; gp += 2) {
        #pragma unroll
        for (int i = 0; i < GS; ++i) step(bufB[i], false);
        if (gp + 2 < ng) {
            #pragma unroll
            for (int i = 0; i < GS; ++i) bufB[i] = axp[(size_t)((gp + 2) * GS + i) * 32];
        }
        if (gp + 1 < ng) {
            #pragma unroll
            for (int i = 0; i < GS; ++i) step(bufA[i], false);
            if (gp + 3 < ng) {
                #pragma unroll
                for (int i = 0; i < GS; ++i) bufA[i] = axp[(size_t)((gp + 3) * GS + i) * 32];
            }
        }
    }

    // save h1 (lower) before the epilogue junks it; then finish GRU2(tcnt-1)
    if (!last && lo) hws[b * 64 + j] = h;
    step(make_float2(0.f, 0.f), false);
    if (!last) {
        if (!lo && j < L2) hws[b * 64 + 32 + j] = h;
        return;
    }

    // ---- tail: FC3+ReLU, FC4, log_softmax (h2 = upper lanes of h) ----
    float s2[L2];
    #pragma unroll
    for (int k = 0; k < L2; ++k) s2[k] = rl(h, 32 + k);
    float a3 = 0.f;
    if (lane < L3) {
        a3 = b3[lane];
        #pragma unroll
        for (int k = 0; k < L2; ++k) a3 = fmaf(s2[k], w3[k * L3 + lane], a3);
        a3 = fmaxf(a3, 0.f);
    }
    float s3[L3];
    #pragma unroll
    for (int k = 0; k < L3; ++k) s3[k] = rl(a3, k);
    float a4 = 0.f;
    if (lane < NCLASS) {
        a4 = b4[lane];
        #pragma unroll
        for (int k = 0; k < L3; ++k) a4 = fmaf(s3[k], w4[k * NCLASS + lane], a4);
    }
    float s4[NCLASS];
    #pragma unroll
    for (int k = 0; k < NCLASS; ++k) s4[k] = rl(a4, k);
    float m = s4[0];
    #pragma unroll
    for (int k = 1; k < NCLASS; ++k) m = fmaxf(m, s4[k]);
    float ss = 0.f;
    #pragma unroll
    for (int k = 0; k < NCLASS; ++k)
        ss += __builtin_amdgcn_exp2f((s4[k] - m) * LOG2E);
    float lse = m + __builtin_amdgcn_logf(ss) * LN2;
    if (lane < NCLASS) outg[b * NCLASS + lane] = s4[lane] - lse;
}

extern "C" void kernel_launch(void* const* d_in, const int* in_sizes, int n_in,
                              void* d_out, int out_size, void* d_ws, size_t ws_size,
                              hipStream_t stream) {
    const float* x   = (const float*)d_in[0];
    const float* wz1 = (const float*)d_in[1];
    const float* bz1 = (const float*)d_in[2];
    const float* wh1 = (const float*)d_in[3];
    const float* bh1 = (const float*)d_in[4];
    const float* wz2 = (const float*)d_in[5];
    const float* bz2 = (const float*)d_in[6];
    const float* wh2 = (const float*)d_in[7];
    const float* bh2 = (const float*)d_in[8];
    const float* w3  = (const float*)d_in[9];
    const float* b3  = (const float*)d_in[10];
    const float* w4  = (const float*)d_in[11];
    const float* b4  = (const float*)d_in[12];
    float* out = (float*)d_out;

    const int Bsz = in_sizes[0] / (T * FBINS);          // 512

    float* hws = (float*)d_ws;                          // Bsz*64 floats h state
    float* axw = hws + (size_t)Bsz * 64;
    const size_t hbytes = (size_t)Bsz * 64 * sizeof(float);
    const size_t per_t  = (size_t)Bsz * 64 * sizeof(float);

    int segT = T;
    if (ws_size < hbytes + (size_t)T * per_t) {
        size_t avail = (ws_size > hbytes) ? ws_size - hbytes : 0;
        size_t s = avail / per_t;
        segT = (s > (size_t)T) ? T : (int)s;
        segT &= ~7;
        if (segT < 8) segT = 8;
    }

    for (int t0 = 0; t0 < T; t0 += segT) {
        const int tc = (T - t0 < segT) ? (T - t0) : segT;
        dim3 g1(Bsz, (tc + TCH - 1) / TCH);
        xproj_kernel<<<g1, dim3(256), 0, stream>>>(x, wz1, bz1, wh1, bh1,
                                                   axw, t0, tc, segT);
        rec_kernel<<<dim3(Bsz), dim3(64), 0, stream>>>(axw,
            wz1, wh1, wz2, bz2, wh2, bh2, w3, b3, w4, b4,
            hws, out, tc, segT, t0 == 0 ? 1 : 0, (t0 + tc >= T) ? 1 : 0);
    }
}

// Round 11
// 298.067 us; speedup vs baseline: 1.3293x; 1.3293x over previous
//
#include <hip/hip_runtime.h>

// 2-layer GRU (T=1000 serial, B=512) + FC + log_softmax.
// Pass 1: ax[b,t] = (x_t @ W1x + b1) * LOG2E-scales -> d_ws, per-lane (z,g).
// Pass 2: one wave per batch element, skewed layers (lanes 0..31 = GRU1 unit j
//         @ step t, lanes 32..51 = GRU2 unit j @ step t-1). The r8 readlane
//         broadcast (52 ops @ ~8cyc = the measured bottleneck) is halved by
//         packing h into f16 PAIRS: one DPP row_shr:1 + one v_cvt_pkrtz per
//         step, then 26 readlanes broadcast (h_2p, h_2p+1) pairs; the dot is
//         52 v_dot2_f32_f16 (f16 mul, exact-in-f32 products, f32 accum).
//         Only the h-part dot is f16; x-part and h state stay fp32.

typedef __fp16 v2h __attribute__((ext_vector_type(2)));

constexpr int FBINS  = 40;
constexpr int L1     = 32;
constexpr int L2     = 20;
constexpr int L3     = 16;
constexpr int NCLASS = 10;
constexpr int T      = 1000;
constexpr int NPAIR  = (L1 + L2) / 2;   // 26 f16-pairs over K
constexpr float LOG2E = 1.4426950408889634f;
constexpr float LN2   = 0.6931471805599453f;

__device__ __forceinline__ float rl(float v, int l) {
    return __uint_as_float(__builtin_amdgcn_readlane(__float_as_uint(v), l));
}

// ---------------- pass 1: x-projection (pre-scaled by LOG2E / 2*LOG2E) ------
constexpr int TCH = 100;
__global__ __launch_bounds__(256) void xproj_kernel(
    const float* __restrict__ xg,
    const float* __restrict__ wz1, const float* __restrict__ bz1,
    const float* __restrict__ wh1, const float* __restrict__ bh1,
    float* __restrict__ ax, int t0, int tcnt, int segcap)
{
    __shared__ float xs[TCH * FBINS];
    const int tid = threadIdx.x, lane = tid & 63;
    const int b   = blockIdx.x;
    const int lt0 = blockIdx.y * TCH;
    const int cnt = min(TCH, tcnt - lt0);
    const float* src = xg + ((size_t)b * T + t0 + lt0) * FBINS;
    const int ndw = cnt * FBINS;
    for (int i = tid; i < ndw; i += 256) xs[i] = src[i];
    __syncthreads();

    const int j = lane & 31;
    const float* wp = (lane < 32) ? wz1 : wh1;   // lane<32: z-gate, else g-gate
    const float scale = (lane < 32) ? LOG2E : (2.0f * LOG2E);
    float w[FBINS];
    #pragma unroll
    for (int k = 0; k < FBINS; ++k) w[k] = wp[k * L1 + j] * scale;
    const float bias = ((lane < 32) ? bz1[j] : bh1[j]) * scale;
    const int slot = j * 2 + (lane >> 5);        // (z,g) interleaved pairs

    const int wv = tid >> 6;
    for (int lt = wv; lt < cnt; lt += 4) {
        const float* xp = xs + lt * FBINS;
        float a0 = bias, a1 = 0.f, a2 = 0.f, a3 = 0.f;
        #pragma unroll
        for (int k = 0; k < FBINS; k += 4) {
            a0 = fmaf(xp[k+0], w[k+0], a0);
            a1 = fmaf(xp[k+1], w[k+1], a1);
            a2 = fmaf(xp[k+2], w[k+2], a2);
            a3 = fmaf(xp[k+3], w[k+3], a3);
        }
        ax[((size_t)b * segcap + lt0 + lt) * 64 + slot] = (a0 + a1) + (a2 + a3);
    }
}

// ---------------- pass 2: skewed recurrence, f16-pair broadcast -------------
constexpr int GS = 8;      // steps per prefetch group (double-buffered)
__global__ __launch_bounds__(64) void rec_kernel(
    const float* __restrict__ ax,
    const float* __restrict__ wz1, const float* __restrict__ wh1,
    const float* __restrict__ wz2, const float* __restrict__ bz2,
    const float* __restrict__ wh2, const float* __restrict__ bh2,
    const float* __restrict__ w3,  const float* __restrict__ b3,
    const float* __restrict__ w4,  const float* __restrict__ b4,
    float* __restrict__ hws, float* __restrict__ outg,
    int tcnt, int segcap, int first, int last)
{
    const int lane = threadIdx.x;
    const int b    = blockIdx.x;
    const int j    = lane & 31;
    const bool lo  = lane < 32;
    const int j2   = (j < L2) ? j : 0;           // clamp junk lanes 52..63

    // per-lane f16-pair weight columns (pre-scaled).
    // lower lane j: GRU1 h-part rows 40..71 of w_*1 (pairs 16..25 zero).
    // upper lane 32+j: GRU2 full rows 0..51 of w_*2.
    v2h wzp[NPAIR], wgp[NPAIR];
    #pragma unroll
    for (int k = 0; k < L1; k += 2) {
        float za = (lo ? wz1[(FBINS + k)     * L1 + j] : wz2[k       * L2 + j2]) * LOG2E;
        float zb = (lo ? wz1[(FBINS + k + 1) * L1 + j] : wz2[(k + 1) * L2 + j2]) * LOG2E;
        float ga = (lo ? wh1[(FBINS + k)     * L1 + j] : wh2[k       * L2 + j2]) * (2.0f * LOG2E);
        float gb = (lo ? wh1[(FBINS + k + 1) * L1 + j] : wh2[(k + 1) * L2 + j2]) * (2.0f * LOG2E);
        wzp[k/2] = __builtin_amdgcn_cvt_pkrtz(za, zb);
        wgp[k/2] = __builtin_amdgcn_cvt_pkrtz(ga, gb);
    }
    #pragma unroll
    for (int k = 0; k < L2; k += 2) {
        float za = lo ? 0.f : wz2[(L1 + k)     * L2 + j2] * LOG2E;
        float zb = lo ? 0.f : wz2[(L1 + k + 1) * L2 + j2] * LOG2E;
        float ga = lo ? 0.f : wh2[(L1 + k)     * L2 + j2] * (2.0f * LOG2E);
        float gb = lo ? 0.f : wh2[(L1 + k + 1) * L2 + j2] * (2.0f * LOG2E);
        wzp[L1/2 + k/2] = __builtin_amdgcn_cvt_pkrtz(za, zb);
        wgp[L1/2 + k/2] = __builtin_amdgcn_cvt_pkrtz(ga, gb);
    }
    const float initZ = bz2[j2] * LOG2E;          // upper lanes only
    const float initG = bh2[j2] * (2.0f * LOG2E);

    const float up0 = first ? 0.f : hws[b * 64 + 32 + j2];   // h2 restore
    float h = lo ? (first ? 0.f : hws[b * 64 + j]) : up0;

    const float2* axp = (const float2*)ax + (size_t)b * segcap * 32 + j;

    auto step = [&](float2 axv, bool fix) {
        // pack (h_lane, h_lane+1) -> f16x2 (DPP row_shr:1 stays in 16-row for
        // all even lanes), broadcast 26 even-lane pairs via readlane -> SGPRs
        int hni = __builtin_amdgcn_mov_dpp(__float_as_int(h), 0x111, 0xf, 0xf, false);
        v2h pk  = __builtin_amdgcn_cvt_pkrtz(h, __int_as_float(hni));
        unsigned pku = __builtin_bit_cast(unsigned, pk);
        unsigned shp[NPAIR];
        #pragma unroll
        for (int p = 0; p < L1 / 2; ++p)
            shp[p] = (unsigned)__builtin_amdgcn_readlane((int)pku, 2 * p);
        #pragma unroll
        for (int p = 0; p < L2 / 2; ++p)
            shp[L1/2 + p] = (unsigned)__builtin_amdgcn_readlane((int)pku, 32 + 2 * p);

        // dot: 52 v_dot2_f32_f16, 4 independent f32 chains
        float az0 = lo ? axv.x : initZ, az1 = 0.f;
        float ag0 = lo ? axv.y : initG, ag1 = 0.f;
        #pragma unroll
        for (int p = 0; p < NPAIR; p += 2) {
            v2h s0 = __builtin_bit_cast(v2h, shp[p]);
            v2h s1 = __builtin_bit_cast(v2h, shp[p + 1]);
            az0 = __builtin_amdgcn_fdot2(s0, wzp[p],     az0, false);
            ag0 = __builtin_amdgcn_fdot2(s0, wgp[p],     ag0, false);
            az1 = __builtin_amdgcn_fdot2(s1, wzp[p + 1], az1, false);
            ag1 = __builtin_amdgcn_fdot2(s1, wgp[p + 1], ag1, false);
        }
        float z = az0 + az1;
        float g = ag0 + ag1;
        // activations (args pre-scaled by LOG2E / 2*LOG2E)
        float ez  = __builtin_amdgcn_exp2f(-z);
        float s   = __builtin_amdgcn_rcpf(1.f + ez);
        float eg  = __builtin_amdgcn_exp2f(-g);
        float r   = __builtin_amdgcn_rcpf(1.f + eg);
        float hp1 = 1.f + h;
        float d   = fmaf(2.f, r, -hp1);           // tanh(g) - h
        h = fmaf(s, d, h);                        // (1-z)h + z*tanh(g)
        if (fix) h = lo ? h : up0;                // round-0 skew fixup
    };

    // ---- pipelined loop, GS-step groups, double-buffered register prefetch
    float2 bufA[GS], bufB[GS];
    const int ng = tcnt / GS;                    // tcnt multiple of 8
    #pragma unroll
    for (int i = 0; i < GS; ++i) bufA[i] = axp[(size_t)i * 32];
    if (1 < ng) {
        #pragma unroll
        for (int i = 0; i < GS; ++i) bufB[i] = axp[(size_t)(GS + i) * 32];
    }

    step(bufA[0], true);                         // round 0: fix junk GRU2 out
    #pragma unroll
    for (int i = 1; i < GS; ++i) step(bufA[i], false);
    if (2 < ng) {
        #pragma unroll
        for (int i = 0; i < GS; ++i) bufA[i] = axp[(size_t)(2 * GS + i) * 32];
    }
    #pragma unroll 1
    for (int gp = 1; gp < ng; gp += 2) {
        #pragma unroll
        for (int i = 0; i < GS; ++i) step(bufB[i], false);
        if (gp + 2 < ng) {
            #pragma unroll
            for (int i = 0; i < GS; ++i) bufB[i] = axp[(size_t)((gp + 2) * GS + i) * 32];
        }
        if (gp + 1 < ng) {
            #pragma unroll
            for (int i = 0; i < GS; ++i) step(bufA[i], false);
            if (gp + 3 < ng) {
                #pragma unroll
                for (int i = 0; i < GS; ++i) bufA[i] = axp[(size_t)((gp + 3) * GS + i) * 32];
            }
        }
    }

    // save h1 (lower) before the epilogue junks it; then finish GRU2(tcnt-1)
    if (!last && lo) hws[b * 64 + j] = h;
    step(make_float2(0.f, 0.f), false);
    if (!last) {
        if (!lo && j < L2) hws[b * 64 + 32 + j] = h;
        return;
    }

    // ---- tail: FC3+ReLU, FC4, log_softmax (h2 = upper lanes of h, fp32) ----
    float s2[L2];
    #pragma unroll
    for (int k = 0; k < L2; ++k) s2[k] = rl(h, 32 + k);
    float a3 = 0.f;
    if (lane < L3) {
        a3 = b3[lane];
        #pragma unroll
        for (int k = 0; k < L2; ++k) a3 = fmaf(s2[k], w3[k * L3 + lane], a3);
        a3 = fmaxf(a3, 0.f);
    }
    float s3[L3];
    #pragma unroll
    for (int k = 0; k < L3; ++k) s3[k] = rl(a3, k);
    float a4 = 0.f;
    if (lane < NCLASS) {
        a4 = b4[lane];
        #pragma unroll
        for (int k = 0; k < L3; ++k) a4 = fmaf(s3[k], w4[k * NCLASS + lane], a4);
    }
    float s4[NCLASS];
    #pragma unroll
    for (int k = 0; k < NCLASS; ++k) s4[k] = rl(a4, k);
    float m = s4[0];
    #pragma unroll
    for (int k = 1; k < NCLASS; ++k) m = fmaxf(m, s4[k]);
    float ss = 0.f;
    #pragma unroll
    for (int k = 0; k < NCLASS; ++k)
        ss += __builtin_amdgcn_exp2f((s4[k] - m) * LOG2E);
    float lse = m + __builtin_amdgcn_logf(ss) * LN2;
    if (lane < NCLASS) outg[b * NCLASS + lane] = s4[lane] - lse;
}

extern "C" void kernel_launch(void* const* d_in, const int* in_sizes, int n_in,
                              void* d_out, int out_size, void* d_ws, size_t ws_size,
                              hipStream_t stream) {
    const float* x   = (const float*)d_in[0];
    const float* wz1 = (const float*)d_in[1];
    const float* bz1 = (const float*)d_in[2];
    const float* wh1 = (const float*)d_in[3];
    const float* bh1 = (const float*)d_in[4];
    const float* wz2 = (const float*)d_in[5];
    const float* bz2 = (const float*)d_in[6];
    const float* wh2 = (const float*)d_in[7];
    const float* bh2 = (const float*)d_in[8];
    const float* w3  = (const float*)d_in[9];
    const float* b3  = (const float*)d_in[10];
    const float* w4  = (const float*)d_in[11];
    const float* b4  = (const float*)d_in[12];
    float* out = (float*)d_out;

    const int Bsz = in_sizes[0] / (T * FBINS);          // 512

    float* hws = (float*)d_ws;                          // Bsz*64 floats h state
    float* axw = hws + (size_t)Bsz * 64;
    const size_t hbytes = (size_t)Bsz * 64 * sizeof(float);
    const size_t per_t  = (size_t)Bsz * 64 * sizeof(float);

    int segT = T;
    if (ws_size < hbytes + (size_t)T * per_t) {
        size_t avail = (ws_size > hbytes) ? ws_size - hbytes : 0;
        size_t s = avail / per_t;
        segT = (s > (size_t)T) ? T : (int)s;
        segT &= ~7;
        if (segT < 8) segT = 8;
    }

    for (int t0 = 0; t0 < T; t0 += segT) {
        const int tc = (T - t0 < segT) ? (T - t0) : segT;
        dim3 g1(Bsz, (tc + TCH - 1) / TCH);
        xproj_kernel<<<g1, dim3(256), 0, stream>>>(x, wz1, bz1, wh1, bh1,
                                                   axw, t0, tc, segT);
        rec_kernel<<<dim3(Bsz), dim3(64), 0, stream>>>(axw,
            wz1, wh1, wz2, bz2, wh2, bh2, w3, b3, w4, b4,
            hws, out, tc, segT, t0 == 0 ? 1 : 0, (t0 + tc >= T) ? 1 : 0);
    }
}